// Round 5
// baseline (4607.304 us; speedup 1.0000x reference)
//
#include <hip/hip_runtime.h>
#include <math.h>

#define NA   360
#define ZPT  8
#define ROWS 24          // v-span bound 19.3 + floor/bilinear/pad
#define COLS 52          // u-span bound 45.3 + floor/bilinear/pad
#define NEL  (ROWS*COLS) // 1248 staged floats per angle
#define PITCHB (COLS*4)

// Cone-beam backprojection, LDS-staged.
// Geometry: dz=dy=dx=2mm, dv=du=2mm, DSO=1000, DSD=1536.
// v = zv*mag + 127.5 in (8.6,246.4) -> v never clamps, v0+1 in-bounds.
// Per (16x16xy-tile, 8z, angle) detector footprint fits ROWSxCOLS (proven:
// u-span<=45.3px, v-span<=19.3px incl. hull conservatism); stage it in LDS.

__device__ __forceinline__ int2 bbox_angle(float c, float s,
    float xclo, float xchi, float yclo, float ychi, float zvlo, float zvhi)
{
    const float a0 = xclo*c, a1 = xchi*c, b0 = yclo*s, b1 = ychi*s;
    const float xr0 = a0+b0, xr1 = a0+b1, xr2 = a1+b0, xr3 = a1+b1;
    const float xmn = fminf(fminf(xr0,xr1), fminf(xr2,xr3));
    const float xmx = fmaxf(fmaxf(xr0,xr1), fmaxf(xr2,xr3));
    const float c0 = yclo*c, c1 = ychi*c, d0 = xclo*s, d1 = xchi*s;
    const float yr0 = c0-d0, yr1 = c0-d1, yr2 = c1-d0, yr3 = c1-d1;
    const float ymn = fminf(fminf(yr0,yr1), fminf(yr2,yr3));
    const float ymx = fmaxf(fmaxf(yr0,yr1), fmaxf(yr2,yr3));
    const float mlo = 1536.f * __builtin_amdgcn_rcpf(1000.f - xmn); // mag increasing in xr
    const float mhi = 1536.f * __builtin_amdgcn_rcpf(1000.f - xmx);
    const float umn = fminf(fminf(ymn*mlo, ymn*mhi), fminf(ymx*mlo, ymx*mhi));
    int u_lo = (int)floorf(fmaf(umn, 0.5f, 127.5f)) - 1;
    u_lo = u_lo < 0 ? 0 : (u_lo > 256-COLS ? 256-COLS : u_lo);
    const float vmn = fminf(fminf(zvlo*mlo, zvlo*mhi), fminf(zvhi*mlo, zvhi*mhi));
    int v_lo = (int)floorf(vmn + 127.5f) - 1;
    v_lo = v_lo < 0 ? 0 : (v_lo > 256-ROWS ? 256-ROWS : v_lo);
    return make_int2(u_lo, v_lo);
}

__device__ __forceinline__ void compute_angle(const float* __restrict__ smb,
    float c, float s, float xc, float yc, float zf0, int u_lo, int v_lo,
    float acc[ZPT])
{
    const float xr  = xc*c + yc*s;
    const float yr  = yc*c - xc*s;
    const float mag = 1536.f * __builtin_amdgcn_rcpf(1000.f - xr);
    const float iu  = fmaf(yr*mag, 0.5f, 127.5f);
    const bool uval = (iu >= 0.f) && (iu <= 255.f);
    const float iuc = fminf(fmaxf(iu, 0.f), 255.f);
    int u0 = (int)iuc; u0 = u0 > 254 ? 254 : u0;
    const float fu  = iuc - (float)u0;
    const float w   = uval ? 1.f : 0.f;
    const float wu1 = fu*w, wu0 = w - wu1;
    const int   ub  = (u0 - u_lo) << 2;                  // byte offset in row
    const float ivb = fmaf(zf0, mag, 127.5f) - (float)v_lo;
    #pragma unroll
    for (int k = 0; k < ZPT; ++k) {
        const float ivl = fmaf((float)k, mag, ivb);
        const int   v0  = (int)ivl;                      // ivl>0 -> trunc==floor
        const float fv  = ivl - (float)v0;
        const float* p  = (const float*)((const char*)smb + (v0*PITCHB + ub));
        const float p00 = p[0], p01 = p[1];              // -> ds_read2_b32
        const float p10 = p[COLS], p11 = p[COLS+1];
        const float q0 = fmaf(fv, p10 - p00, p00);
        const float q1 = fmaf(fv, p11 - p01, p01);
        acc[k] = fmaf(wu0, q0, acc[k]);
        acc[k] = fmaf(wu1, q1, acc[k]);
    }
}

__global__ __launch_bounds__(256, 8) void bp_kernel(const float* __restrict__ proj,
                                                    float* __restrict__ out) {
    __shared__ float2 cs_sh[NA];
    __shared__ float  sm[2][NEL];

    const int tid = threadIdx.y * 16 + threadIdx.x;
    for (int i = tid; i < NA; i += 256) {
        float th = (float)i * (float)(2.0 * M_PI / (double)NA);
        float sv, cv; sincosf(th, &sv, &cv);
        cs_sh[i] = make_float2(cv, sv);
    }
    __syncthreads();

    const int x0 = (blockIdx.x & 7) * 16;
    const int y0 = (blockIdx.x >> 3) * 16;
    const int zb = blockIdx.y * ZPT;
    const int b  = blockIdx.z;

    const float xc  = ((float)(x0 + threadIdx.x) - 63.5f) * 2.f;
    const float yc  = ((float)(y0 + threadIdx.y) - 63.5f) * 2.f;
    const float zf0 = (float)zb - 63.5f;

    const float xclo = ((float)x0 - 63.5f) * 2.f, xchi = xclo + 30.f;
    const float yclo = ((float)y0 - 63.5f) * 2.f, ychi = yclo + 30.f;
    const float zvlo = zf0, zvhi = zf0 + 7.f;

    const float* projB = proj + (size_t)b * (NA * 65536);

    // per-thread staging pattern: element i covers flat idx tid+256*i of [ROWS][COLS]
    int goff[5];
    {
        int r = (tid * 1261) >> 16;       // tid/52 (exact for tid<256)
        int cc = tid - r * 52;
        #pragma unroll
        for (int i = 0; i < 5; ++i) {
            goff[i] = r * 256 + cc;       // detector-row-major offset
            cc += 48; r += 4;             // +256 = 4*52+48
            if (cc >= 52) { cc -= 52; r += 1; }
        }
    }
    const bool last_ok = (tid < NEL - 1024);   // 224

    float acc[ZPT];
    #pragma unroll
    for (int k = 0; k < ZPT; ++k) acc[k] = 0.f;

    float tmp[5];
    // prologue: stage angle 0 into sm[0]
    float2 cs0 = cs_sh[0];
    int2 lo = bbox_angle(cs0.x, cs0.y, xclo, xchi, yclo, ychi, zvlo, zvhi);
    {
        const float* g = projB + lo.y * 256 + lo.x;
        #pragma unroll
        for (int i = 0; i < 4; ++i) tmp[i] = g[goff[i]];
        if (last_ok) tmp[4] = g[goff[4]];
        #pragma unroll
        for (int i = 0; i < 4; ++i) sm[0][tid + 256*i] = tmp[i];
        if (last_ok) sm[0][tid + 1024] = tmp[4];
    }
    __syncthreads();

    int ulo_c = lo.x, vlo_c = lo.y;

    for (int a = 0; a < NA - 1; ++a) {
        // issue next angle's coalesced staging loads (fly under compute)
        float2 csn = cs_sh[a + 1];
        int2 lon = bbox_angle(csn.x, csn.y, xclo, xchi, yclo, ychi, zvlo, zvhi);
        const float* g = projB + (size_t)(a + 1) * 65536 + lon.y * 256 + lon.x;
        #pragma unroll
        for (int i = 0; i < 4; ++i) tmp[i] = g[goff[i]];
        if (last_ok) tmp[4] = g[goff[4]];

        // compute current angle from LDS
        float2 cs = cs_sh[a];
        compute_angle(sm[a & 1], cs.x, cs.y, xc, yc, zf0, ulo_c, vlo_c, acc);

        // late write of staged data, one barrier per angle
        float* smn = sm[(a & 1) ^ 1];
        #pragma unroll
        for (int i = 0; i < 4; ++i) smn[tid + 256*i] = tmp[i];
        if (last_ok) smn[tid + 1024] = tmp[4];
        __syncthreads();
        ulo_c = lon.x; vlo_c = lon.y;
    }
    {
        float2 cs = cs_sh[NA - 1];
        compute_angle(sm[(NA - 1) & 1], cs.x, cs.y, xc, yc, zf0, ulo_c, vlo_c, acc);
    }

    float* o = out + (((size_t)b * 128 + zb) * 128 + (y0 + threadIdx.y)) * 128
                   + (x0 + threadIdx.x);
    #pragma unroll
    for (int k = 0; k < ZPT; ++k) {
        o[(size_t)k * (128 * 128)] = acc[k];
    }
}

extern "C" void kernel_launch(void* const* d_in, const int* in_sizes, int n_in,
                              void* d_out, int out_size, void* d_ws, size_t ws_size,
                              hipStream_t stream) {
    const float* proj = (const float*)d_in[0];
    float* out = (float*)d_out;
    dim3 grid(64, 128 / ZPT, 2);   // 2048 blocks
    dim3 block(16, 16, 1);
    hipLaunchKernelGGL(bp_kernel, grid, block, 0, stream, proj, out);
}

// Round 6
// 847.453 us; speedup vs baseline: 5.4366x; 5.4366x over previous
//
#include <hip/hip_runtime.h>
#include <math.h>

#define NA   360
#define ZPT  8
#define ROWS 24           // compute uses rows 0..22 (span proof below)
#define COLS 52
#define NSTG 1280         // 5*256 staged floats: rows 0..23 full + 32 pad
#define PITCHB (COLS*4)

// Cone-beam backprojection, LDS-staged via global_load_lds (zero-register).
// Geometry: dz=dy=dx=2mm, dv=du=2mm, DSO=1000, DSD=1536, mag in [1.302,1.872].
// iv = zv*mag + 127.5 in (8.6,246.4) -> v never clamps, v0+1 in-bounds.
// Per (16x16 xy-tile, 8z, angle): iv span <= 19.24 (z-span 7*mag + |zv|*dmag),
// window [v_lo, v_lo+22] covers all taps (v_lo = floor(min)-1, clamp [0,231]);
// u window COLS=52 proven sufficient empirically (R5 passed, absmax 0.25,
// exhaustive over 360 angles x 2048 blocks). Max staged global offset:
// (231+24)*256 + 204+31 = 65515 < 65536 -> always inside the angle slab.

typedef __attribute__((address_space(1))) const void gas_t;
typedef __attribute__((address_space(3))) void las_t;

__device__ __forceinline__ int2 bbox_angle(float c, float s,
    float xclo, float xchi, float yclo, float ychi, float zvlo, float zvhi)
{
    const float a0 = xclo*c, a1 = xchi*c, b0 = yclo*s, b1 = ychi*s;
    const float xr0 = a0+b0, xr1 = a0+b1, xr2 = a1+b0, xr3 = a1+b1;
    const float xmn = fminf(fminf(xr0,xr1), fminf(xr2,xr3));
    const float xmx = fmaxf(fmaxf(xr0,xr1), fmaxf(xr2,xr3));
    const float c0 = yclo*c, c1 = ychi*c, d0 = xclo*s, d1 = xchi*s;
    const float yr0 = c0-d0, yr1 = c0-d1, yr2 = c1-d0, yr3 = c1-d1;
    const float ymn = fminf(fminf(yr0,yr1), fminf(yr2,yr3));
    const float ymx = fmaxf(fmaxf(yr0,yr1), fmaxf(yr2,yr3));
    const float mlo = 1536.f * __builtin_amdgcn_rcpf(1000.f - xmn);
    const float mhi = 1536.f * __builtin_amdgcn_rcpf(1000.f - xmx);
    const float umn = fminf(fminf(ymn*mlo, ymn*mhi), fminf(ymx*mlo, ymx*mhi));
    int u_lo = (int)floorf(fmaf(umn, 0.5f, 127.5f)) - 1;
    u_lo = u_lo < 0 ? 0 : (u_lo > 256-COLS ? 256-COLS : u_lo);
    const float vmn = fminf(fminf(zvlo*mlo, zvlo*mhi), fminf(zvhi*mlo, zvhi*mhi));
    int v_lo = (int)floorf(vmn + 127.5f) - 1;
    v_lo = v_lo < 0 ? 0 : (v_lo > 231 ? 231 : v_lo);   // 231: pad row stays in-slab
    return make_int2(u_lo, v_lo);
}

__device__ __forceinline__ void stage5(const float* g, float* lds_wave,
                                       const int goffB[5]) {
    #pragma unroll
    for (int i = 0; i < 5; ++i) {
        __builtin_amdgcn_global_load_lds(
            (gas_t*)((const char*)g + goffB[i]),
            (las_t*)(lds_wave + i * 256),
            4, 0, 0);
    }
}

__device__ __forceinline__ void compute_angle(const float* __restrict__ smb,
    float c, float s, float xc, float yc, float zf0, int u_lo, int v_lo,
    float acc[ZPT])
{
    const float xr  = xc*c + yc*s;
    const float yr  = yc*c - xc*s;
    const float mag = 1536.f * __builtin_amdgcn_rcpf(1000.f - xr);
    const float iu  = fmaf(yr*mag, 0.5f, 127.5f);
    const bool uval = (iu >= 0.f) && (iu <= 255.f);
    const float iuc = fminf(fmaxf(iu, 0.f), 255.f);
    int u0 = (int)iuc; u0 = u0 > 254 ? 254 : u0;
    const float fu  = iuc - (float)u0;
    const float w   = uval ? 1.f : 0.f;
    const float wu1 = fu*w, wu0 = w - wu1;
    const int   ub  = (u0 - u_lo) << 2;                 // byte offset in row
    const float ivb = fmaf(zf0, mag, 127.5f) - (float)v_lo;
    #pragma unroll
    for (int k = 0; k < ZPT; ++k) {
        const float ivl = fmaf((float)k, mag, ivb);
        const int   v0  = (int)ivl;                     // >0 -> trunc==floor
        const float fv  = ivl - (float)v0;
        const char* p   = (const char*)smb + (v0*PITCHB + ub);
        const float p00 = *(const float*)p;
        const float p01 = *(const float*)(p + 4);
        const float p10 = *(const float*)(p + PITCHB);
        const float p11 = *(const float*)(p + PITCHB + 4);
        const float q0 = fmaf(fv, p10 - p00, p00);
        const float q1 = fmaf(fv, p11 - p01, p01);
        acc[k] = fmaf(wu0, q0, acc[k]);
        acc[k] = fmaf(wu1, q1, acc[k]);
    }
}

__global__ __launch_bounds__(256, 4) void bp_kernel(const float* __restrict__ proj,
                                                    float* __restrict__ out) {
    __shared__ float2 cs_sh[NA];
    __shared__ int2   bb_sh[NA];
    __shared__ float  patch[2][NSTG];

    const int tid = threadIdx.y * 16 + threadIdx.x;

    const int zg = blockIdx.x;            // z-group fastest -> XCD = zg%8 shares v-band
    const int t  = blockIdx.y;            // xy tile
    const int b  = blockIdx.z;
    const int x0 = (t & 7) * 16;
    const int y0 = (t >> 3) * 16;
    const int zb = zg * ZPT;

    const float zf0  = (float)zb - 63.5f;
    const float xclo = ((float)x0 - 63.5f) * 2.f, xchi = xclo + 30.f;
    const float yclo = ((float)y0 - 63.5f) * 2.f, ychi = yclo + 30.f;

    for (int i = tid; i < NA; i += 256) {
        float th = (float)i * (float)(2.0 * M_PI / (double)NA);
        float sv, cv; sincosf(th, &sv, &cv);
        cs_sh[i] = make_float2(cv, sv);
        bb_sh[i] = bbox_angle(cv, sv, xclo, xchi, yclo, ychi, zf0, zf0 + 7.f);
    }
    __syncthreads();

    // staging pattern: flat patch idx = tid + 256*i, patch is [25][52] row-major
    int goffB[5];
    #pragma unroll
    for (int i = 0; i < 5; ++i) {
        const int flat = tid + 256 * i;
        const int r  = (flat * 1261) >> 16;   // flat/52, exact for flat<1280
        const int cc = flat - r * 52;
        goffB[i] = (r * 256 + cc) * 4;        // detector-row-major, bytes
    }

    const float* projB = proj + (size_t)b * (NA * 65536);
    const float xc = ((float)(x0 + threadIdx.x) - 63.5f) * 2.f;
    const float yc = ((float)(y0 + threadIdx.y) - 63.5f) * 2.f;

    float* wv0 = &patch[0][tid & 192];        // wave-uniform LDS bases
    float* wv1 = &patch[1][tid & 192];

    float acc[ZPT];
    #pragma unroll
    for (int k = 0; k < ZPT; ++k) acc[k] = 0.f;

    // prologue: stage angle 0 into patch[0]
    {
        const int2 lo = bb_sh[0];
        stage5(projB + (lo.y << 8) + lo.x, wv0, goffB);
    }
    __syncthreads();   // drains vmcnt -> patch[0] ready

    for (int a = 0; a < NA; a += 2) {
        {   // stage a+1 -> patch[1] while computing a from patch[0]
            const int2 lo = bb_sh[a + 1];
            stage5(projB + (a + 1) * 65536 + (lo.y << 8) + lo.x, wv1, goffB);
        }
        {
            const float2 cs = cs_sh[a];
            const int2   lo = bb_sh[a];
            compute_angle(patch[0], cs.x, cs.y, xc, yc, zf0, lo.x, lo.y, acc);
        }
        __syncthreads();
        if (a + 2 < NA) {   // stage a+2 -> patch[0] while computing a+1 from patch[1]
            const int2 lo = bb_sh[a + 2];
            stage5(projB + (a + 2) * 65536 + (lo.y << 8) + lo.x, wv0, goffB);
        }
        {
            const float2 cs = cs_sh[a + 1];
            const int2   lo = bb_sh[a + 1];
            compute_angle(patch[1], cs.x, cs.y, xc, yc, zf0, lo.x, lo.y, acc);
        }
        __syncthreads();
    }

    float* o = out + (((size_t)b * 128 + zb) * 128 + (y0 + threadIdx.y)) * 128
                   + (x0 + threadIdx.x);
    #pragma unroll
    for (int k = 0; k < ZPT; ++k) {
        o[(size_t)k * (128 * 128)] = acc[k];
    }
}

extern "C" void kernel_launch(void* const* d_in, const int* in_sizes, int n_in,
                              void* d_out, int out_size, void* d_ws, size_t ws_size,
                              hipStream_t stream) {
    const float* proj = (const float*)d_in[0];
    float* out = (float*)d_out;
    dim3 grid(128 / ZPT, 64, 2);   // (z-groups, xy-tiles, batch) = 2048 blocks
    dim3 block(16, 16, 1);
    hipLaunchKernelGGL(bp_kernel, grid, block, 0, stream, proj, out);
}